// Round 1
// baseline (346.958 us; speedup 1.0000x reference)
//
#include <hip/hip_runtime.h>

constexpr int NG  = 2048;  // graphs
constexpr int NN  = 64;    // nodes per graph
constexpr int DD  = 128;   // node dim
constexpr int KK  = 128;   // attention dim
constexpr int OUTD = 10;   // output dim

// ---------------------------------------------------------------------------
// Kernel 1: fold K out of the problem.
//   A[o][f][e] = sum_k Wa[k*D+f] * W1[o*K*D + k*D + e]
//   c[o][e]    = sum_k b_att[k]  * W1[o*K*D + k*D + e]
// Grid: OUT*D blocks (o = blk>>7, f = blk&127), 128 threads (e).
// ---------------------------------------------------------------------------
__global__ __launch_bounds__(128)
void precompute_kernel(const float* __restrict__ Wa,
                       const float* __restrict__ b_att,
                       const float* __restrict__ W1,
                       float* __restrict__ A,
                       float* __restrict__ c)
{
    const int o = blockIdx.x >> 7;
    const int f = blockIdx.x & 127;
    const int e = threadIdx.x;
    const float* __restrict__ W1o = W1 + (size_t)o * (KK * DD);

    float acc = 0.f, cacc = 0.f;
    for (int k = 0; k < KK; ++k) {
        const float w1 = W1o[k * DD + e];
        acc  += Wa[k * DD + f] * w1;
        cacc += b_att[k] * w1;
    }
    A[((size_t)o * DD + f) * DD + e] = acc;
    if (f == 0) c[o * DD + e] = cacc;
}

// ---------------------------------------------------------------------------
// Kernel 2: one block per graph.
//   Gs = round(100*X^T X)/100   (LDS, 128x128)
//   s[e] = colsum(Gs)
//   H[f,e] = sum_d Gs[d,f]*Gs[d,e]   (register 4x8 tiles, never materialized)
//   out[g,o] = <A_o, H> + <c_o, s> + b1[o]
// ---------------------------------------------------------------------------
__global__ __launch_bounds__(512)
void graph_kernel(const float* __restrict__ x,
                  const float* __restrict__ A,
                  const float* __restrict__ c,
                  const float* __restrict__ bias1,
                  float* __restrict__ out)
{
    __shared__ float xs[NN * DD];     // 32 KB
    __shared__ float Gs[DD * DD];     // 64 KB
    __shared__ float ssum[DD];
    __shared__ float red[OUTD][8];

    const int g   = blockIdx.x;
    const int tid = threadIdx.x;
    const float* __restrict__ xg = x + (size_t)g * NN * DD;

    // stage x: 8192 floats, float4-coalesced
    {
        const float4* __restrict__ src = (const float4*)xg;
        float4* dst = (float4*)xs;
        for (int i = tid; i < NN * DD / 4; i += 512) dst[i] = src[i];
    }
    __syncthreads();

    // thread tile: 4 rows (r0..r0+3) x 8 cols (c0..c0+7)
    const int tr = tid >> 4;       // 0..31
    const int tc = tid & 15;       // 0..15
    const int r0 = tr * 4;
    const int c0 = tc * 8;

    // ---- gram = X^T X (tile), then quantize into Gs ----
    float acc[4][8];
#pragma unroll
    for (int i = 0; i < 4; ++i)
#pragma unroll
        for (int j = 0; j < 8; ++j) acc[i][j] = 0.f;

    for (int n = 0; n < NN; ++n) {
        const float4 av = *(const float4*)&xs[n * DD + r0];
        const float4 b0 = *(const float4*)&xs[n * DD + c0];
        const float4 b1v = *(const float4*)&xs[n * DD + c0 + 4];
        const float a[4] = {av.x, av.y, av.z, av.w};
        const float b[8] = {b0.x, b0.y, b0.z, b0.w, b1v.x, b1v.y, b1v.z, b1v.w};
#pragma unroll
        for (int i = 0; i < 4; ++i)
#pragma unroll
            for (int j = 0; j < 8; ++j) acc[i][j] += a[i] * b[j];
    }

#pragma unroll
    for (int i = 0; i < 4; ++i)
#pragma unroll
        for (int j = 0; j < 8; ++j)
            Gs[(r0 + i) * DD + c0 + j] = rintf(acc[i][j] * 100.f) / 100.f;
    __syncthreads();

    // ---- column sums (threads 0..127; stride-1 reads, conflict-free) ----
    if (tid < DD) {
        float s = 0.f;
        for (int d = 0; d < DD; ++d) s += Gs[d * DD + tid];
        ssum[tid] = s;
    }

    // ---- H = G^T G tile + contraction with A ----
    float h[4][8];
#pragma unroll
    for (int i = 0; i < 4; ++i)
#pragma unroll
        for (int j = 0; j < 8; ++j) h[i][j] = 0.f;

    for (int d = 0; d < DD; ++d) {
        const float4 av = *(const float4*)&Gs[d * DD + r0];
        const float4 b0 = *(const float4*)&Gs[d * DD + c0];
        const float4 b1v = *(const float4*)&Gs[d * DD + c0 + 4];
        const float a[4] = {av.x, av.y, av.z, av.w};
        const float b[8] = {b0.x, b0.y, b0.z, b0.w, b1v.x, b1v.y, b1v.z, b1v.w};
#pragma unroll
        for (int i = 0; i < 4; ++i)
#pragma unroll
            for (int j = 0; j < 8; ++j) h[i][j] += a[i] * b[j];
    }

    float po[OUTD];
#pragma unroll
    for (int o = 0; o < OUTD; ++o) {
        const float* __restrict__ Ao = A + ((size_t)o * DD + r0) * DD + c0;
        float s = 0.f;
#pragma unroll
        for (int i = 0; i < 4; ++i) {
            const float4 a0 = *(const float4*)&Ao[i * DD];
            const float4 a1 = *(const float4*)&Ao[i * DD + 4];
            s += a0.x * h[i][0] + a0.y * h[i][1] + a0.z * h[i][2] + a0.w * h[i][3]
               + a1.x * h[i][4] + a1.y * h[i][5] + a1.z * h[i][6] + a1.w * h[i][7];
        }
        po[o] = s;
    }

    // ---- block reduction: 10 scalars over 512 threads ----
    const int lane = tid & 63;
    const int wave = tid >> 6;
#pragma unroll
    for (int o = 0; o < OUTD; ++o) {
        float v = po[o];
        v += __shfl_down(v, 32, 64);
        v += __shfl_down(v, 16, 64);
        v += __shfl_down(v, 8, 64);
        v += __shfl_down(v, 4, 64);
        v += __shfl_down(v, 2, 64);
        v += __shfl_down(v, 1, 64);
        if (lane == 0) red[o][wave] = v;
    }
    __syncthreads();

    if (tid < OUTD) {
        float t = 0.f;
#pragma unroll
        for (int w = 0; w < 8; ++w) t += red[tid][w];
        float sc = 0.f;
        for (int e = 0; e < DD; ++e) sc += ssum[e] * c[tid * DD + e];
        out[(size_t)g * OUTD + tid] = t + sc + bias1[tid];
    }
}

// ---------------------------------------------------------------------------
extern "C" void kernel_launch(void* const* d_in, const int* in_sizes, int n_in,
                              void* d_out, int out_size, void* d_ws, size_t ws_size,
                              hipStream_t stream)
{
    const float* x     = (const float*)d_in[0];
    const float* Wa    = (const float*)d_in[1];
    const float* b_att = (const float*)d_in[2];
    const float* W1    = (const float*)d_in[3];
    const float* bias1 = (const float*)d_in[4];
    float* out = (float*)d_out;

    float* A = (float*)d_ws;                       // 10*128*128 floats = 640 KB
    float* c = A + (size_t)OUTD * DD * DD;         // 10*128 floats

    precompute_kernel<<<OUTD * DD, 128, 0, stream>>>(Wa, b_att, W1, A, c);
    graph_kernel<<<NG, 512, 0, stream>>>(x, A, c, bias1, out);
}

// Round 2
// 63.507 us; speedup vs baseline: 5.4633x; 5.4633x over previous
//
#include <hip/hip_runtime.h>

typedef __attribute__((ext_vector_type(8)))  __bf16 bf16x8;
typedef __attribute__((ext_vector_type(4)))  __bf16 bf16x4;
typedef __attribute__((ext_vector_type(16))) float  f32x16;

constexpr int NG  = 2048;
constexpr int NN  = 64;
constexpr int DD  = 128;
constexpr int KK  = 128;
constexpr int OUTD = 10;

// upper-triangular 32x32 tile list: t -> (ti, tj), ti <= tj
__device__ __host__ inline void tileOf(int t, int& ti, int& tj) {
    if (t < 4)      { ti = 0; tj = t;     }
    else if (t < 7) { ti = 1; tj = t - 3; }
    else if (t < 9) { ti = 2; tj = t - 5; }
    else            { ti = 3; tj = 3;     }
}

// XOR swizzle (element units; 2B elems -> byte ^= (r&7)<<4): spreads rows across 16B slots
__device__ inline int xtIdx(int r, int c) { return r * 64  + (c ^ ((r & 7) << 3)); }
__device__ inline int gIdx (int r, int c) { return r * 128 + (c ^ ((r & 7) << 3)); }

// ---------------------------------------------------------------------------
// Kernel 1a: A[o][f][e] = sum_k Wa[k,f] * W1[o, k*D+e];  c[o][e] = sum_k b[k] * W1[o,k*D+e]
// ---------------------------------------------------------------------------
__global__ __launch_bounds__(128)
void precompute_kernel(const float* __restrict__ Wa,
                       const float* __restrict__ b_att,
                       const float* __restrict__ W1,
                       float* __restrict__ A,
                       float* __restrict__ c)
{
    const int o = blockIdx.x >> 7;
    const int f = blockIdx.x & 127;
    const int e = threadIdx.x;
    const float* __restrict__ W1o = W1 + (size_t)o * (KK * DD);

    float acc = 0.f, cacc = 0.f;
    for (int k = 0; k < KK; ++k) {
        const float w1 = W1o[k * DD + e];
        acc  += Wa[k * DD + f] * w1;
        cacc += b_att[k] * w1;
    }
    A[((size_t)o * DD + f) * DD + e] = acc;
    if (f == 0) c[o * DD + e] = cacc;
}

// ---------------------------------------------------------------------------
// Kernel 1b: symmetrized S packed in 32x32x16 D-fragment order, bf16.
//   S[f,e] = A[f,e]+A[e,f] (f<e) ; A[f,f] (f==e) ; 0 (f>e, diag tiles)
//   Sp[((o*10+t)*64 + lane)*16 + r] = S[ti*32 + (r&3)+8*(r>>2)+4*(lane>>5), tj*32 + (lane&31)]
// ---------------------------------------------------------------------------
__global__ __launch_bounds__(256)
void pack_kernel(const float* __restrict__ A, __bf16* __restrict__ Sp)
{
    const int b = blockIdx.x;
    const int o = b / 10, t = b - o * 10;
    int ti, tj; tileOf(t, ti, tj);
    const int l  = threadIdx.x & 63;
    const int rq = threadIdx.x >> 6;      // 0..3
    const int e  = tj * 32 + (l & 31);
    const float* __restrict__ Ao = A + (size_t)o * DD * DD;

    bf16x4 p;
#pragma unroll
    for (int j = 0; j < 4; ++j) {
        const int f = ti * 32 + j + 8 * rq + 4 * (l >> 5);
        float v;
        if (f < e)       v = Ao[f * DD + e] + Ao[e * DD + f];
        else if (f == e) v = Ao[f * DD + f];
        else             v = 0.f;
        p[j] = (__bf16)v;
    }
    *(bf16x4*)&Sp[(size_t)((o * 10 + t) * 64 + l) * 16 + rq * 4] = p;
}

// ---------------------------------------------------------------------------
// Kernel 2: one block per graph. 512 threads = 8 waves.
// ---------------------------------------------------------------------------
__global__ __launch_bounds__(512)
void graph_kernel(const float* __restrict__ x,
                  const __bf16* __restrict__ Sp,
                  const float* __restrict__ cg,
                  const float* __restrict__ bias1,
                  float* __restrict__ out)
{
    __shared__ __align__(16) __bf16 XtL[DD * NN];   // 16 KB, X^T (f-major, n fast), swizzled
    __shared__ __align__(16) __bf16 GL [DD * DD];   // 32 KB, quantized gram (symmetric), swizzled
    __shared__ float sLds[DD];
    __shared__ float red[OUTD][8];

    const int g   = blockIdx.x;
    const int tid = threadIdx.x;
    const int w   = tid >> 6;
    const int l   = tid & 63;
    const int l31 = l & 31;
    const int l5  = l >> 5;
    const float* __restrict__ xg = x + (size_t)g * NN * DD;

    // ---- phase 0: load X column-wise, store X^T as bf16 (RNE) ----
    {
        const int f = tid & 127, half = tid >> 7;  // 16 n's per thread
        float v[16];
#pragma unroll
        for (int i = 0; i < 16; ++i) v[i] = xg[(half * 16 + i) * DD + f];
        bf16x8 p0, p1;
#pragma unroll
        for (int i = 0; i < 8; ++i) { p0[i] = (__bf16)v[i]; p1[i] = (__bf16)v[8 + i]; }
        *(bf16x8*)&XtL[xtIdx(f, half * 16)]     = p0;
        *(bf16x8*)&XtL[xtIdx(f, half * 16 + 8)] = p1;
    }
    __syncthreads();

    // ---- phase 1: gram tiles. wave w: ti = w&3, tj = {2*(w>>2), +1} ----
    const int ti  = w & 3;
    const int tj0 = (w >> 2) * 2;
    f32x16 acc0, acc1;
#pragma unroll
    for (int i = 0; i < 16; ++i) { acc0[i] = 0.f; acc1[i] = 0.f; }
    {
        const int arow  = ti  * 32 + l31;
        const int brow0 = tj0 * 32 + l31;
#pragma unroll
        for (int ks = 0; ks < 4; ++ks) {
            const int kc = ks * 16 + l5 * 8;
            bf16x8 a  = *(const bf16x8*)&XtL[xtIdx(arow, kc)];
            bf16x8 b0 = *(const bf16x8*)&XtL[xtIdx(brow0, kc)];
            bf16x8 b1 = *(const bf16x8*)&XtL[xtIdx(brow0 + 32, kc)];
            acc0 = __builtin_amdgcn_mfma_f32_32x32x16_bf16(a, b0, acc0, 0, 0, 0);
            acc1 = __builtin_amdgcn_mfma_f32_32x32x16_bf16(a, b1, acc1, 0, 0, 0);
        }
    }

    // ---- phase 2: quantize, store transposed (G symmetric) as bf16 ----
#pragma unroll
    for (int tt = 0; tt < 2; ++tt) {
        const int e = (tj0 + tt) * 32 + l31;       // row of G (transposed write)
#pragma unroll
        for (int g2 = 0; g2 < 4; ++g2) {
            bf16x4 p;
#pragma unroll
            for (int j = 0; j < 4; ++j) {
                const float av = tt ? acc1[g2 * 4 + j] : acc0[g2 * 4 + j];
                p[j] = (__bf16)(rintf(av * 100.f) * 0.01f);
            }
            const int fbase = ti * 32 + g2 * 8 + l5 * 4;
            *(bf16x4*)&GL[gIdx(e, fbase)] = p;
        }
    }
    __syncthreads();   // G complete

    // ---- phase 3: H = G*G upper-tri tiles; waves 6,7 also colsum s ----
    if (w >= 6) {
        const int e = (w - 6) * 64 + l;   // 0..127
        float ssum = 0.f;
#pragma unroll
        for (int i = 0; i < 16; ++i) {
            bf16x8 gv = *(const bf16x8*)&GL[e * 128 + i * 8];  // swizzle = row bijection
#pragma unroll
            for (int j = 0; j < 8; ++j) ssum += (float)gv[j];
        }
        sLds[e] = ssum;
    }

    int hti0, htj0; tileOf(w, hti0, htj0);
    f32x16 hacc0, hacc1;
#pragma unroll
    for (int i = 0; i < 16; ++i) { hacc0[i] = 0.f; hacc1[i] = 0.f; }
    {
        const int ra = hti0 * 32 + l31, rb = htj0 * 32 + l31;
#pragma unroll
        for (int ks = 0; ks < 8; ++ks) {
            const int kc = ks * 16 + l5 * 8;
            bf16x8 a = *(const bf16x8*)&GL[gIdx(ra, kc)];
            bf16x8 b = *(const bf16x8*)&GL[gIdx(rb, kc)];
            hacc0 = __builtin_amdgcn_mfma_f32_32x32x16_bf16(a, b, hacc0, 0, 0, 0);
        }
    }
    if (w < 2) {
        int ti1, tj1; tileOf(8 + w, ti1, tj1);
        const int ra = ti1 * 32 + l31, rb = tj1 * 32 + l31;
#pragma unroll
        for (int ks = 0; ks < 8; ++ks) {
            const int kc = ks * 16 + l5 * 8;
            bf16x8 a = *(const bf16x8*)&GL[gIdx(ra, kc)];
            bf16x8 b = *(const bf16x8*)&GL[gIdx(rb, kc)];
            hacc1 = __builtin_amdgcn_mfma_f32_32x32x16_bf16(a, b, hacc1, 0, 0, 0);
        }
    }
    __syncthreads();   // s ready

    // ---- phase 4: contraction with S_pack (+ c.s on wave 0) ----
    float po[OUTD];
#pragma unroll
    for (int o = 0; o < OUTD; ++o) po[o] = 0.f;

#pragma unroll
    for (int o = 0; o < OUTD; ++o) {
        const __bf16* sp = Sp + (size_t)((o * 10 + w) * 64 + l) * 16;
        bf16x8 s0 = *(const bf16x8*)&sp[0];
        bf16x8 s1 = *(const bf16x8*)&sp[8];
        float t = 0.f;
#pragma unroll
        for (int j = 0; j < 8; ++j) t += (float)s0[j] * hacc0[j];
#pragma unroll
        for (int j = 0; j < 8; ++j) t += (float)s1[j] * hacc0[8 + j];
        po[o] += t;
    }
    if (w < 2) {
        const int t2 = 8 + w;
#pragma unroll
        for (int o = 0; o < OUTD; ++o) {
            const __bf16* sp = Sp + (size_t)((o * 10 + t2) * 64 + l) * 16;
            bf16x8 s0 = *(const bf16x8*)&sp[0];
            bf16x8 s1 = *(const bf16x8*)&sp[8];
            float t = 0.f;
#pragma unroll
            for (int j = 0; j < 8; ++j) t += (float)s0[j] * hacc1[j];
#pragma unroll
            for (int j = 0; j < 8; ++j) t += (float)s1[j] * hacc1[8 + j];
            po[o] += t;
        }
    }
    if (w == 0) {
#pragma unroll
        for (int o = 0; o < OUTD; ++o)
            po[o] += cg[o * DD + l] * sLds[l] + cg[o * DD + 64 + l] * sLds[64 + l];
    }

    // ---- phase 5: reduce ----
#pragma unroll
    for (int o = 0; o < OUTD; ++o) {
        float v = po[o];
        v += __shfl_down(v, 32, 64);
        v += __shfl_down(v, 16, 64);
        v += __shfl_down(v, 8, 64);
        v += __shfl_down(v, 4, 64);
        v += __shfl_down(v, 2, 64);
        v += __shfl_down(v, 1, 64);
        if (l == 0) red[o][w] = v;
    }
    __syncthreads();

    if (tid < OUTD) {
        float t = bias1[tid];
#pragma unroll
        for (int ww = 0; ww < 8; ++ww) t += red[tid][ww];
        out[(size_t)g * OUTD + tid] = t;
    }
}

// ---------------------------------------------------------------------------
extern "C" void kernel_launch(void* const* d_in, const int* in_sizes, int n_in,
                              void* d_out, int out_size, void* d_ws, size_t ws_size,
                              hipStream_t stream)
{
    const float* x     = (const float*)d_in[0];
    const float* Wa    = (const float*)d_in[1];
    const float* b_att = (const float*)d_in[2];
    const float* W1    = (const float*)d_in[3];
    const float* bias1 = (const float*)d_in[4];
    float* out = (float*)d_out;

    float*  A  = (float*)d_ws;                       // 163840 f32 (640 KB)
    float*  c  = A + (size_t)OUTD * DD * DD;         // 1280 f32
    __bf16* Sp = (__bf16*)(c + OUTD * DD);           // 102400 bf16 (200 KB)

    precompute_kernel<<<OUTD * DD, 128, 0, stream>>>(Wa, b_att, W1, A, c);
    pack_kernel<<<100, 256, 0, stream>>>(A, Sp);
    graph_kernel<<<NG, 512, 0, stream>>>(x, Sp, c, bias1, out);
}